// Round 8
// baseline (485.138 us; speedup 1.0000x reference)
//
#include <hip/hip_runtime.h>

typedef unsigned long long u64;
typedef unsigned int u32;

namespace {
constexpr int kB = 16;
constexpr int kN = 8732;
constexpr int kC = 20;
constexpr int kRow = 25;      // 1 + C + 4
constexpr int kKeep = 300;    // NNS_K
constexpr int kTot = 200;     // K_TOTAL
constexpr float kConf = 0.01f;
// fl32(inter/union) > 0.45f  <=>  inter/union > 0.45f + ulp/2 (0.45f mantissa even,
// tie rounds down). kThr = 30198989 * 2^-26 exactly; 26-bit x 24-bit product
// is <= 50 bits -> exact in f64, so the f64 compare is an exact emulation.
constexpr double kThr = 0.45000000298023223876953125;

constexpr int TPB = 512;           // 8 waves/block -> 2.5 waves/SIMD on 320 blocks
constexpr int NW = TPB / 64;
constexpr int NBKT = 4096;         // score-bit buckets (bits>>14), range fits 3442
constexpr int kPool = 2048;        // sorted-candidate pool per tranche (top scores)
constexpr int CH = 512;            // phase-2 chunk = one block-wide sweep
constexpr int kFlat = kC * kKeep;  // 6000
constexpr int kNIter = (kN + TPB - 1) / TPB;  // 18
}

// exact emulation of reference: (union>0) && fl32(inter/union) > 0.45f
// (union >= 0 provable by rounding monotonicity; union==0 => inter==0 => false)
__device__ __forceinline__ bool iou_gt(float ay1, float ax1, float ay2, float ax2, float aa,
                                       float by1, float bx1, float by2, float bx2, float ba) {
  const float ty1 = fmaxf(ay1, by1);
  const float tx1 = fmaxf(ax1, bx1);
  const float ty2 = fminf(ay2, by2);
  const float tx2 = fminf(ax2, bx2);
  const float dy = fmaxf(__fsub_rn(ty2, ty1), 0.0f);
  const float dx = fmaxf(__fsub_rn(tx2, tx1), 0.0f);
  const float inter = __fmul_rn(dy, dx);
  const float uni = __fsub_rn(__fadd_rn(aa, ba), inter);
  return ((double)inter > kThr * (double)uni);
}

// bucket by high bits of score: monotone DESC (bucket 0 = highest scores).
// valid for s in (0.01, 1.0]: bits>>14 in [61583, 65024] -> bkt in [0, 3441].
__device__ __forceinline__ int bkt_of(float s) {
  return 65024 - (int)(__float_as_uint(s) >> 14);
}

// packed in-bucket sort key: same bucket => scores share bits[31:14], so
// (low14 desc, 16383-idx desc) == (score desc, idx asc). idx recoverable.
__device__ __forceinline__ u32 key_of(float s, int idx) {
  return ((__float_as_uint(s) & 0x3FFFu) << 14) | (u32)(16383 - idx);
}

// (score, flat-idx) strict ordering: higher score wins; ties -> lower idx.
__device__ __forceinline__ bool pgt(float as, u32 ai, float bs, u32 bi) {
  return (as > bs) || ((as == bs) && (ai < bi));
}

// exclusive prefix sum over hist[NBKT]; 512 threads own 8 buckets each.
// returns total count. hist[i] becomes the exclusive start of bucket i.
__device__ int excl_scan_hist(u32* hist, u32* wsum, int tid) {
  const int base = tid * 8;
  u32 loc[8];
  u32 s = 0;
#pragma unroll
  for (int i = 0; i < 8; ++i) { loc[i] = hist[base + i]; s += loc[i]; }
  int v = (int)s;
  const int lane = tid & 63;
#pragma unroll
  for (int off = 1; off < 64; off <<= 1) {
    const int u = __shfl_up(v, off);
    if (lane >= off) v += u;
  }
  if (lane == 63) wsum[tid >> 6] = (u32)v;
  __syncthreads();
  u32 woff = 0, total = 0;
#pragma unroll
  for (int w = 0; w < NW; ++w) {
    const u32 t = wsum[w];
    total += t;
    if (w < (tid >> 6)) woff += t;
  }
  u32 run = woff + (u32)v - s;
#pragma unroll
  for (int i = 0; i < 8; ++i) { hist[base + i] = run; run += loc[i]; }
  __syncthreads();
  return (int)total;
}

// Transpose pass: scores_t[b][c][n] (coalesced per-class columns) + box SoA.
__global__ __launch_bounds__(256) void prep_kernel(const float* __restrict__ in,
                                                   float* __restrict__ st,
                                                   float* __restrict__ py1,
                                                   float* __restrict__ px1,
                                                   float* __restrict__ py2,
                                                   float* __restrict__ px2) {
  const int b = blockIdx.y;
  const int n0 = blockIdx.x * 256;
  const int tid = threadIdx.x;
  const int rows = min(256, kN - n0);

  __shared__ float tile[256 * kRow];
  const float* __restrict__ src = in + ((size_t)b * kN + n0) * kRow;
  const int total = rows * kRow;
  for (int i = tid; i < total; i += 256) tile[i] = src[i];
  __syncthreads();
  if (tid < rows) {
    const int n = n0 + tid;
    const float* row = &tile[tid * kRow];
#pragma unroll
    for (int c = 0; c < kC; ++c)
      st[((size_t)b * kC + c) * kN + n] = row[1 + c];
    py1[(size_t)b * kN + n] = row[21];
    px1[(size_t)b * kN + n] = row[22];
    py2[(size_t)b * kN + n] = row[23];
    px2[(size_t)b * kN + n] = row[24];
  }
}

// One block per (b,c) task.
// Tranche loop (typically runs ONCE): histogram CDF picks the bucket range
// holding the top <=2048 candidates; only those are scattered+sorted; the
// chunked greedy scan consumes them; if (rare/adversarial data) cnt<300 when
// the pool is exhausted, the next bucket range is processed identically.
template <bool X>
__global__ __launch_bounds__(TPB, 4) void nms_kernel(const float* __restrict__ in,
                                                     const float* __restrict__ st,
                                                     const float* __restrict__ py1,
                                                     const float* __restrict__ px1,
                                                     const float* __restrict__ py2,
                                                     const float* __restrict__ px2,
                                                     float* __restrict__ ws_s,
                                                     float* __restrict__ ws_b) {
  const int task = blockIdx.x;
  const int b = task / kC;
  const int c = task - b * kC;
  const int tid = threadIdx.x;
  const int lane = tid & 63;
  const int wid = tid >> 6;
  const float* __restrict__ base_in = in + (size_t)b * kN * kRow;
  const float* __restrict__ stc = st + ((size_t)b * kC + c) * kN;
  const size_t bo = (size_t)b * kN;

  __shared__ __align__(16) unsigned char ovl[32768];  // hist u32[4096] | rows u64[512*8]
  __shared__ u32 skey[kPool];                         // 8 KB sorted keys (pool)
  __shared__ float cy1[CH], cx1[CH], cy2[CH], cx2[CH], car[CH];  // 10 KB
  __shared__ u32 supp[CH];                            // 2 KB
  __shared__ u32 selr[CH];                            // 2 KB resolve result map
  __shared__ float sel_y1[kKeep], sel_x1[kKeep], sel_y2[kKeep], sel_x2[kKeep],
      sel_ar[kKeep];                                  // 6 KB
  __shared__ u32 wsum[NW];
  __shared__ int s_red[NW];
  __shared__ int s_nc;

  u32* hist = (u32*)ovl;
  u64* rows = (u64*)ovl;

  float* __restrict__ out_s = ws_s + (size_t)task * kKeep;
  float* __restrict__ out_b = ws_b + (size_t)task * kKeep * 4;

  int cnt = 0;
  int blo = 0;
  while (cnt < kKeep && blo < NBKT) {
    // ---- histogram (re-built per tranche; scatter mutates it) ----
    for (int i = tid; i < NBKT; i += TPB) hist[i] = 0;
    __syncthreads();
    for (int k = 0; k < kNIter; ++k) {
      const int n = tid + k * TPB;
      if (n < kN) {
        const float s = X ? stc[n] : base_in[(size_t)n * kRow + 1 + c];
        if (s > kConf) atomicAdd(&hist[bkt_of(s)], 1u);
      }
    }
    __syncthreads();
    const int ncand = excl_scan_hist(hist, wsum, tid);
    const int base = (int)hist[blo];  // exclusive start of bucket blo
    if (ncand == 0 || base >= ncand) break;
    // ---- find bend: max bucket bound with pool count <= kPool ----
    int bestb = blo + 1;
#pragma unroll
    for (int i = 0; i < 8; ++i) {
      const int bb = tid * 8 + i;
      if (bb > blo && (int)hist[bb] - base <= kPool) bestb = max(bestb, bb);
    }
    if (ncand - base <= kPool) bestb = NBKT;
#pragma unroll
    for (int off = 32; off; off >>= 1) bestb = max(bestb, __shfl_xor(bestb, off));
    if (lane == 0) s_red[wid] = bestb;
    __syncthreads();
    int bend = s_red[0];
#pragma unroll
    for (int w = 1; w < NW; ++w) bend = max(bend, s_red[w]);
    const int poolN =
        min(((bend == NBKT) ? ncand : (int)hist[bend]) - base, kPool);
    // ---- scatter candidates in bucket range [blo, bend) ----
    for (int k = 0; k < kNIter; ++k) {
      const int n = tid + k * TPB;
      if (n < kN) {
        const float s = X ? stc[n] : base_in[(size_t)n * kRow + 1 + c];
        if (s > kConf) {
          const int bb = bkt_of(s);
          if (bb >= blo && bb < bend) {
            const u32 pos = atomicAdd(&hist[bb], 1u) - (u32)base;
            if (pos < (u32)kPool) skey[pos] = key_of(s, n);
          }
        }
      }
    }
    __syncthreads();
    // ---- in-bucket insertion sort, descending u32 key (exact order) ----
    for (int bb = blo + tid; bb < bend; bb += TPB) {
      int s0 = (bb == blo) ? 0 : (int)hist[bb - 1] - base;
      int e0 = (int)hist[bb] - base;
      s0 = min(s0, kPool);
      e0 = min(e0, kPool);
      for (int i = s0 + 1; i < e0; ++i) {
        const u32 kk = skey[i];
        int j = i - 1;
        while (j >= s0 && kk > skey[j]) { skey[j + 1] = skey[j]; --j; }
        skey[j + 1] = kk;
      }
    }
    __syncthreads();  // hist region becomes `rows` scratch below

    // ---- phase 2: chunked sequential greedy scan over the sorted pool ----
    int basec = 0;
    while (cnt < kKeep && basec < poolN) {
      const int rank = basec + tid;
      const bool havec = rank < poolN;
      const int lim = min(CH, poolN - basec);
      float ey1 = 0, ex1 = 0, ey2 = 0, ex2 = 0, ea = 0;
      int eidx = 0;
      if (havec) {
        eidx = 16383 - (int)(skey[rank] & 0x3FFFu);
        if (X) {
          ey1 = py1[bo + eidx]; ex1 = px1[bo + eidx];
          ey2 = py2[bo + eidx]; ex2 = px2[bo + eidx];
        } else {
          const float* r = base_in + (size_t)eidx * kRow;
          ey1 = r[21]; ex1 = r[22]; ey2 = r[23]; ex2 = r[24];
        }
        ea = __fmul_rn(__fsub_rn(ey2, ey1), __fsub_rn(ex2, ex1));
      }
      cy1[tid] = ey1; cx1[tid] = ex1; cy2[tid] = ey2; cx2[tid] = ex2;
      car[tid] = ea;
      // test vs already-selected set (LDS broadcast reads; independent iters)
      bool sup = !havec;
#pragma unroll 4
      for (int i = 0; i < cnt; ++i) {
        sup = sup | iou_gt(ey1, ex1, ey2, ex2, ea, sel_y1[i], sel_x1[i],
                           sel_y2[i], sel_x2[i], sel_ar[i]);
      }
      supp[tid] = sup ? 1u : 0u;
      __syncthreads();  // A: chunk boxes + supp visible
      // in-chunk suppression mask row (vs earlier candidates in this chunk);
      // words written straight to LDS (no runtime-indexed register array)
      {
        const int jl = havec ? tid : 0;
#pragma unroll
        for (int w = 0; w < 8; ++w) {
          u64 rw = 0;
          const int tb = w * 64;
          const int te = min(64, jl - tb);
          for (int t2 = 0; t2 < te; ++t2) {
            const int t = tb + t2;
            const bool kill = iou_gt(ey1, ex1, ey2, ex2, ea, cy1[t], cx1[t],
                                     cy2[t], cx2[t], car[t]);
            rw |= kill ? (1ull << t2) : 0ull;
          }
          rows[(size_t)tid * 8 + w] = rw;
        }
      }
      __syncthreads();  // B: rows visible
      // serial resolve on tid 0 only (others' issue slots feed the co-resident
      // block); result map in selr[], final count in s_nc.
      if (tid == 0) {
        int nc = cnt;
        u64 A0 = 0, A1 = 0, A2 = 0, A3 = 0, A4 = 0, A5 = 0, A6 = 0, A7 = 0;
#define RESOLVE_WORD(W, AW)                                                    \
  {                                                                            \
    const int tb = (W)*64;                                                     \
    const int te = min(64, lim - tb);                                          \
    u64 curm = 0;                                                              \
    for (int t2 = 0; t2 < te; ++t2) {                                          \
      const int t = tb + t2;                                                   \
      bool ok = (supp[t] == 0u) && (nc < kKeep);                               \
      if (ok) {                                                                \
        const u64* rp = &rows[(size_t)t * 8];                                  \
        u64 h = (rp[0] & A0) | (rp[1] & A1) | (rp[2] & A2) | (rp[3] & A3) |    \
                (rp[4] & A4) | (rp[5] & A5) | (rp[6] & A6) | (rp[7] & A7);     \
        h |= rp[W] & curm;                                                     \
        ok = (h == 0ull);                                                      \
      }                                                                        \
      selr[t] = ok ? (u32)(nc + 1) : 0u;                                       \
      if (ok) { curm |= 1ull << t2; ++nc; }                                    \
    }                                                                          \
    AW = curm;                                                                 \
  }
        RESOLVE_WORD(0, A0)
        RESOLVE_WORD(1, A1)
        RESOLVE_WORD(2, A2)
        RESOLVE_WORD(3, A3)
        RESOLVE_WORD(4, A4)
        RESOLVE_WORD(5, A5)
        RESOLVE_WORD(6, A6)
        RESOLVE_WORD(7, A7)
#undef RESOLVE_WORD
        s_nc = nc;
      }
      __syncthreads();  // C: selr + s_nc visible
      if (havec) {
        const int ms = (int)selr[tid] - 1;
        if (ms >= 0) {
          sel_y1[ms] = ey1; sel_x1[ms] = ex1;
          sel_y2[ms] = ey2; sel_x2[ms] = ex2;
          sel_ar[ms] = ea;
          out_s[ms] = X ? stc[eidx] : base_in[(size_t)eidx * kRow + 1 + c];
          out_b[(size_t)ms * 4 + 0] = ey1;
          out_b[(size_t)ms * 4 + 1] = ex1;
          out_b[(size_t)ms * 4 + 2] = ey2;
          out_b[(size_t)ms * 4 + 3] = ex2;
        }
      }
      cnt = s_nc;  // uniform
      basec += CH;
      __syncthreads();  // D: sel arrays visible; chunk scratch reusable
    }
    blo = bend;
  }
  // empty slots
  for (int i = cnt + tid; i < kKeep; i += TPB) out_s[i] = -1.0f;
}

// One wave per batch: ws_s[task] is already sorted (score desc, idx asc) by
// construction, so top-200 is a 20-way merge of sorted lists. Lane l < 20
// owns list l. head+hnext and their boxes are prefetched into registers so
// each round's critical path is just the butterfly reduce (no memory wait).
__global__ __launch_bounds__(64) void topk_kernel(const float* __restrict__ ws_s,
                                                  const float* __restrict__ ws_b,
                                                  float* __restrict__ out) {
  const int b = blockIdx.x;
  const int lane = threadIdx.x;
  const float* __restrict__ ss = ws_s + (size_t)b * kFlat;
  const float* __restrict__ bb = ws_b + (size_t)b * kFlat * 4;
  float* __restrict__ ob = out + (size_t)b * kTot * 6;

  __shared__ float ls[kFlat];  // [c][slot] == flat order, 24 KB

  for (int i = lane; i < kFlat; i += 64) ls[i] = ss[i];
  __syncthreads();

  int ptr = 0;
  float head = -2.0f, hnext = -2.0f;
  u32 hf = 0xFFFFFFFFu;
  float q0 = 0, q1 = 0, q2 = 0, q3 = 0;      // head's box
  float p0 = 0, p1 = 0, p2 = 0, p3 = 0;      // hnext's box
  if (lane < kC) {
    const u32 f0 = (u32)(lane * kKeep);
    head = ls[f0];
    hf = f0;
    hnext = ls[f0 + 1];
    q0 = bb[(size_t)f0 * 4 + 0]; q1 = bb[(size_t)f0 * 4 + 1];
    q2 = bb[(size_t)f0 * 4 + 2]; q3 = bb[(size_t)f0 * 4 + 3];
    p0 = bb[(size_t)(f0 + 1) * 4 + 0]; p1 = bb[(size_t)(f0 + 1) * 4 + 1];
    p2 = bb[(size_t)(f0 + 1) * 4 + 2]; p3 = bb[(size_t)(f0 + 1) * 4 + 3];
  }

  int r = 0;
  for (; r < kTot; ++r) {
    float bs = head;
    u32 bf = hf;
#pragma unroll
    for (int off = 32; off; off >>= 1) {
      const float os = __shfl_xor(bs, off);
      const u32 of = __shfl_xor(bf, off);
      const bool take = pgt(os, of, bs, bf);
      bs = take ? os : bs;
      bf = take ? of : bf;
    }
    if (bs <= 0.0f) break;  // uniform: only empty (-1) heads remain
    if (hf == bf) {         // unique winner lane; everything needed is in regs
      ob[r * 6 + 0] = (float)(lane + 1);  // class id = list id + 1
      ob[r * 6 + 1] = bs;
      ob[r * 6 + 2] = fminf(fmaxf(q0, 0.0f), 1.0f);
      ob[r * 6 + 3] = fminf(fmaxf(q1, 0.0f), 1.0f);
      ob[r * 6 + 4] = fminf(fmaxf(q2, 0.0f), 1.0f);
      ob[r * 6 + 5] = fminf(fmaxf(q3, 0.0f), 1.0f);
      ++ptr;
      head = hnext;                        // ready in regs: no LDS wait
      hf = (u32)(lane * kKeep + ptr);
      q0 = p0; q1 = p1; q2 = p2; q3 = p3;
      const int nx = ptr + 1;
      if (nx < kKeep) {                    // issue prefetch; used >=1 round later
        const u32 fn = (u32)(lane * kKeep + nx);
        hnext = ls[fn];
        p0 = bb[(size_t)fn * 4 + 0]; p1 = bb[(size_t)fn * 4 + 1];
        p2 = bb[(size_t)fn * 4 + 2]; p3 = bb[(size_t)fn * 4 + 3];
      } else {
        hnext = -2.0f;
      }
    }
  }
  // invalid rows: class = 0+1 = 1, score 0, boxes 0
  for (int idx = r * 6 + lane; idx < kTot * 6; idx += 64) {
    ob[idx] = ((idx % 6) == 0) ? 1.0f : 0.0f;
  }
}

extern "C" void kernel_launch(void* const* d_in, const int* in_sizes, int n_in,
                              void* d_out, int out_size, void* d_ws, size_t ws_size,
                              hipStream_t stream) {
  const float* in = (const float*)d_in[0];
  float* out = (float*)d_out;
  float* ws_s = (float*)d_ws;                    // 96000 floats
  float* ws_b = ws_s + (size_t)kB * kC * kKeep;  // 384000 floats
  float* st = ws_b + (size_t)kB * kC * kKeep * 4;          // 2,794,240 floats
  float* py1 = st + (size_t)kB * kC * kN;                  // 139,712 each
  float* px1 = py1 + (size_t)kB * kN;
  float* py2 = px1 + (size_t)kB * kN;
  float* px2 = py2 + (size_t)kB * kN;
  const size_t needed =
      ((size_t)kB * kC * kKeep * 5 + (size_t)kB * kC * kN + (size_t)kB * kN * 4) *
      sizeof(float);
  if (ws_size >= needed) {
    prep_kernel<<<dim3((kN + 255) / 256, kB), dim3(256), 0, stream>>>(
        in, st, py1, px1, py2, px2);
    nms_kernel<true><<<dim3(kB * kC), dim3(TPB), 0, stream>>>(
        in, st, py1, px1, py2, px2, ws_s, ws_b);
  } else {
    nms_kernel<false><<<dim3(kB * kC), dim3(TPB), 0, stream>>>(
        in, nullptr, nullptr, nullptr, nullptr, nullptr, ws_s, ws_b);
  }
  topk_kernel<<<dim3(kB), dim3(64), 0, stream>>>(ws_s, ws_b, out);
}

// Round 9
// 195.818 us; speedup vs baseline: 2.4775x; 2.4775x over previous
//
#include <hip/hip_runtime.h>

typedef unsigned long long u64;
typedef unsigned int u32;

namespace {
constexpr int kB = 16;
constexpr int kN = 8732;
constexpr int kC = 20;
constexpr int kRow = 25;      // 1 + C + 4
constexpr int kKeep = 300;    // NNS_K
constexpr int kTot = 200;     // K_TOTAL
constexpr float kConf = 0.01f;
// fl32(inter/union) > 0.45f  <=>  inter/union > 0.45f + ulp/2 (0.45f mantissa even,
// tie rounds down). kThr = 30198989 * 2^-26 exactly; 26-bit x 24-bit product
// is <= 50 bits -> exact in f64, so the f64 compare is an exact emulation.
constexpr double kThr = 0.45000000298023223876953125;

constexpr int TPB = 512;
constexpr int NW = TPB / 64;                  // 8 waves
constexpr int NBKT = 4096;                    // score buckets (bits>>14)
constexpr int kPool = 2048;                   // sorted pool per tranche
constexpr int kFlat = kC * kKeep;             // 6000
constexpr int kNIter = (kN + TPB - 1) / TPB;  // 18
}

// exact emulation of reference: (union>0) && fl32(inter/union) > 0.45f
// (union >= 0 provable by rounding monotonicity; union==0 => inter==0 => false)
// box layout: float4 = (y1, x1, y2, x2)
__device__ __forceinline__ bool iou_gt4(const float4 a, const float aa,
                                        const float4 b, const float ba) {
  const float ty1 = fmaxf(a.x, b.x);
  const float tx1 = fmaxf(a.y, b.y);
  const float ty2 = fminf(a.z, b.z);
  const float tx2 = fminf(a.w, b.w);
  const float dy = fmaxf(__fsub_rn(ty2, ty1), 0.0f);
  const float dx = fmaxf(__fsub_rn(tx2, tx1), 0.0f);
  const float inter = __fmul_rn(dy, dx);
  const float uni = __fsub_rn(__fadd_rn(aa, ba), inter);
  return ((double)inter > kThr * (double)uni);
}

// bucket by high bits of score: monotone DESC (bucket 0 = highest scores).
__device__ __forceinline__ int bkt_of(float s) {
  return 65024 - (int)(__float_as_uint(s) >> 14);
}
// packed in-bucket key: (low14 desc, 16383-idx desc) == (score desc, idx asc)
__device__ __forceinline__ u32 key_of(float s, int idx) {
  return ((__float_as_uint(s) & 0x3FFFu) << 14) | (u32)(16383 - idx);
}

// exclusive prefix sum over hist[NBKT]; 512 threads own 8 buckets each.
__device__ int excl_scan_hist(u32* hist, u32* wsum, int tid) {
  const int base = tid * 8;
  u32 loc[8];
  u32 s = 0;
#pragma unroll
  for (int i = 0; i < 8; ++i) { loc[i] = hist[base + i]; s += loc[i]; }
  int v = (int)s;
  const int lane = tid & 63;
#pragma unroll
  for (int off = 1; off < 64; off <<= 1) {
    const int u = __shfl_up(v, off);
    if (lane >= off) v += u;
  }
  if (lane == 63) wsum[tid >> 6] = (u32)v;
  __syncthreads();
  u32 woff = 0, total = 0;
#pragma unroll
  for (int w = 0; w < NW; ++w) {
    const u32 t = wsum[w];
    total += t;
    if (w < (tid >> 6)) woff += t;
  }
  u32 run = woff + (u32)v - s;
#pragma unroll
  for (int i = 0; i < 8; ++i) { hist[base + i] = run; run += loc[i]; }
  __syncthreads();
  return (int)total;
}

// Transpose pass: scores_t[b][c][n] + packed float4 boxes pbox[b][n].
__global__ __launch_bounds__(256) void prep_kernel(const float* __restrict__ in,
                                                   float* __restrict__ st,
                                                   float4* __restrict__ pbox) {
  const int b = blockIdx.y;
  const int n0 = blockIdx.x * 256;
  const int tid = threadIdx.x;
  const int rows = min(256, kN - n0);

  __shared__ float tile[256 * kRow];
  const float* __restrict__ src = in + ((size_t)b * kN + n0) * kRow;
  const int total = rows * kRow;
  for (int i = tid; i < total; i += 256) tile[i] = src[i];
  __syncthreads();
  if (tid < rows) {
    const int n = n0 + tid;
    const float* row = &tile[tid * kRow];
#pragma unroll
    for (int c = 0; c < kC; ++c)
      st[((size_t)b * kC + c) * kN + n] = row[1 + c];
    pbox[(size_t)b * kN + n] = make_float4(row[21], row[22], row[23], row[24]);
  }
}

// One block per (b,c) task.
// Phase 1 (per tranche): bucket-histogram CDF picks the bucket window holding
// the top <=2048 candidates; scatter+insertion-sort gives the exact
// (score desc, idx asc) order. Pool boxes/areas/scores prefetched to LDS.
// Phase 2: groups of 64 candidates. All 512 threads compute sup-vs-selected
// (8 segments each) + in-group kill bit-rows; wave 0 does a ballot-serial
// resolve (exact greedy, register-only). Writes deferred to the end.
template <bool X>
__global__ __launch_bounds__(TPB, 4) void nms_kernel(const float* __restrict__ in,
                                                     const float* __restrict__ st,
                                                     const float4* __restrict__ pbox,
                                                     float* __restrict__ ws_s,
                                                     float* __restrict__ ws_b) {
  const int task = blockIdx.x;
  const int b = task / kC;
  const int c = task - b * kC;
  const int tid = threadIdx.x;
  const float* __restrict__ base_in = in + (size_t)b * kN * kRow;
  const float* __restrict__ stc = st + ((size_t)b * kC + c) * kN;
  const size_t bo = (size_t)b * kN;

  __shared__ __align__(16) unsigned char ovl[49152];  // hist(16K) | pool(48K)
  __shared__ u32 skey[kPool];                         // 8 KB
  __shared__ float4 sel_box[kKeep];                   // 4.8 KB
  __shared__ float sel_ar[kKeep];                     // 1.2 KB
  __shared__ float sel_sc[kKeep];                     // 1.2 KB
  __shared__ u32 supp8[NW * 64];                      // 2 KB
  __shared__ u64 grp8[NW * 64];                       // 4 KB
  __shared__ u32 wsum[NW];
  __shared__ int s_red[NW];
  __shared__ int s_nc;

  u32* hist = (u32*)ovl;
  float4* gbox = (float4*)ovl;          // 2048 * 16 = 32 KB
  float* gar = (float*)(ovl + 32768);   // 8 KB
  float* gsc = (float*)(ovl + 40960);   // 8 KB

  const int lane = tid & 63;
  const int wid = tid >> 6;

  int cnt = 0;
  int blo = 0;
  while (cnt < kKeep && blo < NBKT) {
    // ---- histogram ----
    for (int i = tid; i < NBKT; i += TPB) hist[i] = 0;
    __syncthreads();
    for (int k = 0; k < kNIter; ++k) {
      const int n = tid + k * TPB;
      if (n < kN) {
        const float s = X ? stc[n] : base_in[(size_t)n * kRow + 1 + c];
        if (s > kConf) atomicAdd(&hist[bkt_of(s)], 1u);
      }
    }
    __syncthreads();
    const int ncand = excl_scan_hist(hist, wsum, tid);
    const int base = (int)hist[blo];
    if (ncand == 0 || base >= ncand) break;
    // ---- bend: max bucket bound with window count <= kPool ----
    int bestb = blo + 1;
#pragma unroll
    for (int i = 0; i < 8; ++i) {
      const int bb = tid * 8 + i;
      if (bb > blo && (int)hist[bb] - base <= kPool) bestb = max(bestb, bb);
    }
    if (ncand - base <= kPool) bestb = NBKT;
#pragma unroll
    for (int off = 32; off; off >>= 1) bestb = max(bestb, __shfl_xor(bestb, off));
    if (lane == 0) s_red[wid] = bestb;
    __syncthreads();
    int bend = s_red[0];
#pragma unroll
    for (int w = 1; w < NW; ++w) bend = max(bend, s_red[w]);
    const int poolN =
        min(((bend == NBKT) ? ncand : (int)hist[bend]) - base, kPool);
    // ---- scatter window [blo, bend) ----
    for (int k = 0; k < kNIter; ++k) {
      const int n = tid + k * TPB;
      if (n < kN) {
        const float s = X ? stc[n] : base_in[(size_t)n * kRow + 1 + c];
        if (s > kConf) {
          const int bb = bkt_of(s);
          if (bb >= blo && bb < bend) {
            const u32 pos = atomicAdd(&hist[bb], 1u) - (u32)base;
            if (pos < (u32)kPool) skey[pos] = key_of(s, n);
          }
        }
      }
    }
    __syncthreads();
    // ---- in-bucket insertion sort (desc u32 key) ----
    for (int bb = blo + tid; bb < bend; bb += TPB) {
      int s0 = (bb == blo) ? 0 : (int)hist[bb - 1] - base;
      int e0 = (int)hist[bb] - base;
      s0 = min(s0, kPool);
      e0 = min(e0, kPool);
      for (int i = s0 + 1; i < e0; ++i) {
        const u32 kk = skey[i];
        int j = i - 1;
        while (j >= s0 && kk > skey[j]) { skey[j + 1] = skey[j]; --j; }
        skey[j + 1] = kk;
      }
    }
    __syncthreads();  // hist dead -> pool arrays overlay it
    // ---- pool prefetch: boxes, areas, scores ----
    for (int i = tid; i < poolN; i += TPB) {
      const int eidx = 16383 - (int)(skey[i] & 0x3FFFu);
      float4 bx;
      float s;
      if (X) {
        bx = pbox[bo + eidx];
        s = stc[eidx];
      } else {
        const float* r = base_in + (size_t)eidx * kRow;
        bx = make_float4(r[21], r[22], r[23], r[24]);
        s = r[1 + c];
      }
      gbox[i] = bx;
      gar[i] = __fmul_rn(__fsub_rn(bx.z, bx.x), __fsub_rn(bx.w, bx.y));
      gsc[i] = s;
    }
    __syncthreads();

    // ---- phase 2: groups of 64 ----
    int g0 = 0;
    while (cnt < kKeep && g0 < poolN) {
      const int i = g0 + lane;
      u32 sup = 1u;
      u64 rowbits = 0;
      if (i < poolN) {
        sup = 0u;
        const float4 eb = gbox[i];
        const float ea = gar[i];
        for (int j = wid; j < cnt; j += NW)
          sup |= iou_gt4(eb, ea, sel_box[j], sel_ar[j]) ? 1u : 0u;
        for (int t2 = wid; t2 < lane; t2 += NW)
          rowbits |= iou_gt4(eb, ea, gbox[g0 + t2], gar[g0 + t2])
                         ? (1ull << t2)
                         : 0ull;
      }
      supp8[wid * 64 + lane] = sup;
      grp8[wid * 64 + lane] = rowbits;
      __syncthreads();  // A: partials visible
      if (tid < 64) {   // wave 0 ballot-resolve (exact sequential greedy)
        u32 sp = 0;
        u64 row = 0;
#pragma unroll
        for (int s2 = 0; s2 < NW; ++s2) {
          sp |= supp8[s2 * 64 + tid];
          row |= grp8[s2 * 64 + tid];
        }
        u64 pend = __ballot(sp == 0u);
        u64 acc = 0;
        int nc = cnt;
        while (pend != 0ull && nc < kKeep) {
          const int cur = __ffsll(pend) - 1;
          const u64 cb = 1ull << cur;
          acc |= cb;
          ++nc;
          const u64 killed = __ballot(((row >> cur) & 1ull) != 0ull);
          pend &= ~(killed | cb);
        }
        if ((acc >> tid) & 1ull) {
          const int slot = cnt + (int)__popcll(acc & ((1ull << tid) - 1ull));
          const int ii = g0 + tid;
          sel_box[slot] = gbox[ii];
          sel_ar[slot] = gar[ii];
          sel_sc[slot] = gsc[ii];
        }
        if (tid == 0) s_nc = nc;
      }
      __syncthreads();  // B: sel + s_nc visible
      cnt = s_nc;
      g0 += 64;
    }
    blo = bend;
  }

  // ---- final writeout (bulk, coalesced-ish) ----
  float* __restrict__ out_s = ws_s + (size_t)task * kKeep;
  float* __restrict__ out_b = ws_b + (size_t)task * kKeep * 4;
  for (int i = tid; i < kKeep; i += TPB) {
    if (i < cnt) {
      out_s[i] = sel_sc[i];
      *(float4*)&out_b[(size_t)i * 4] = sel_box[i];
    } else {
      out_s[i] = -1.0f;
    }
  }
}

// One wave per batch: 20-way merge of the sorted per-class lists.
// Heads live in LDS; ALL lanes redundantly argmax 20 broadcast reads (no
// dependent shfl chain); winner advances its own pointer (static registers).
// Box gather + output formatting deferred to a parallel pass after the loop.
__global__ __launch_bounds__(64) void topk_kernel(const float* __restrict__ ws_s,
                                                  const float* __restrict__ ws_b,
                                                  float* __restrict__ out) {
  const int b = blockIdx.x;
  const int lane = threadIdx.x;
  const float* __restrict__ ss = ws_s + (size_t)b * kFlat;
  const float4* __restrict__ bb4 = (const float4*)ws_b + (size_t)b * kFlat;
  float* __restrict__ ob = out + (size_t)b * kTot * 6;

  __shared__ float ls[kFlat];  // 24 KB scores in flat order
  __shared__ float hd[kC];
  __shared__ u32 win[kTot];

  for (int i = lane; i < kFlat; i += 64) ls[i] = ss[i];
  __syncthreads();
  if (lane < kC) hd[lane] = ls[lane * kKeep];
  __syncthreads();

  int ptr = 0;
  int r = 0;
  for (; r < kTot; ++r) {
    // redundant argmax over the 20 heads (broadcast LDS reads, strict > keeps
    // the lowest class => lowest flat idx on exact score ties)
    float m = -2.0f;
    int w = -1;
#pragma unroll
    for (int c2 = 0; c2 < kC; ++c2) {
      const float v = hd[c2];
      if (v > m) { m = v; w = c2; }
    }
    if (m <= 0.0f) break;  // only empties remain
    if (lane == w) {
      win[r] = (u32)(lane * kKeep + ptr);
      ++ptr;
      hd[lane] = (ptr < kKeep) ? ls[lane * kKeep + ptr] : -2.0f;
    }
    __syncthreads();
  }

  // parallel output pass
  for (int rr = lane; rr < r; rr += 64) {
    const u32 f = win[rr];
    const float4 bx = bb4[f];
    ob[rr * 6 + 0] = (float)(f / kKeep + 1);  // class id + 1
    ob[rr * 6 + 1] = ls[f];
    ob[rr * 6 + 2] = fminf(fmaxf(bx.x, 0.0f), 1.0f);
    ob[rr * 6 + 3] = fminf(fmaxf(bx.y, 0.0f), 1.0f);
    ob[rr * 6 + 4] = fminf(fmaxf(bx.z, 0.0f), 1.0f);
    ob[rr * 6 + 5] = fminf(fmaxf(bx.w, 0.0f), 1.0f);
  }
  // invalid rows: class = 0+1 = 1, score 0, boxes 0
  for (int idx = r * 6 + lane; idx < kTot * 6; idx += 64) {
    ob[idx] = ((idx % 6) == 0) ? 1.0f : 0.0f;
  }
}

extern "C" void kernel_launch(void* const* d_in, const int* in_sizes, int n_in,
                              void* d_out, int out_size, void* d_ws, size_t ws_size,
                              hipStream_t stream) {
  const float* in = (const float*)d_in[0];
  float* out = (float*)d_out;
  float* ws_s = (float*)d_ws;                      // 96,000 floats
  float* ws_b = ws_s + (size_t)kB * kC * kKeep;    // 384,000 floats
  float* st = ws_b + (size_t)kB * kC * kKeep * 4;  // 2,794,240 floats
  float4* pbox = (float4*)(st + (size_t)kB * kC * kN);  // 139,712 float4
  const size_t needed =
      ((size_t)kB * kC * kKeep * 5 + (size_t)kB * kC * kN + (size_t)kB * kN * 4) *
      sizeof(float);
  if (ws_size >= needed) {
    prep_kernel<<<dim3((kN + 255) / 256, kB), dim3(256), 0, stream>>>(in, st,
                                                                      pbox);
    nms_kernel<true><<<dim3(kB * kC), dim3(TPB), 0, stream>>>(in, st, pbox,
                                                              ws_s, ws_b);
  } else {
    nms_kernel<false><<<dim3(kB * kC), dim3(TPB), 0, stream>>>(
        in, nullptr, nullptr, ws_s, ws_b);
  }
  topk_kernel<<<dim3(kB), dim3(64), 0, stream>>>(ws_s, ws_b, out);
}